// Round 1
// baseline (321.978 us; speedup 1.0000x reference)
//
#include <hip/hip_runtime.h>
#include <cstdint>

#define D_MODEL 1024
#define N_HEADS 16
#define D_K     64
#define BATCH   2
#define SEQ     2048
#define TOKENS  (BATCH * SEQ)
#define LN_EPS  1e-5f

typedef __bf16 bf16x8 __attribute__((ext_vector_type(8)));
typedef float  floatx4 __attribute__((ext_vector_type(4)));

__device__ __forceinline__ unsigned short f2bf(float f) {
  union { float f; unsigned u; } v; v.f = f;
  unsigned r = v.u + 0x7fffu + ((v.u >> 16) & 1u);
  return (unsigned short)(r >> 16);
}

// ---------------- weight fp32 -> bf16 (4 x 1M elems, concatenated dst) ----
__global__ __launch_bounds__(256) void convw_kernel(
    const float* __restrict__ s0, const float* __restrict__ s1,
    const float* __restrict__ s2, const float* __restrict__ s3,
    unsigned short* __restrict__ dst) {
  int wsel = blockIdx.x >> 10;                       // 1024 blocks per weight
  const float* s = (wsel == 0) ? s0 : (wsel == 1) ? s1 : (wsel == 2) ? s2 : s3;
  unsigned short* d = dst + ((size_t)wsel << 20);
  int i = ((blockIdx.x & 1023) << 8) + threadIdx.x;  // float4 index
  float4 v = reinterpret_cast<const float4*>(s)[i];
  ushort4 o;
  o.x = f2bf(v.x); o.y = f2bf(v.y); o.z = f2bf(v.z); o.w = f2bf(v.w);
  reinterpret_cast<ushort4*>(d)[i] = o;
}

// ---------------- LayerNorm: one 1024-wide row per block -> bf16 ----------
__global__ __launch_bounds__(256) void ln_kernel(
    const float* __restrict__ h, const float* __restrict__ w,
    const float* __restrict__ b, unsigned short* __restrict__ hn) {
  int row = blockIdx.x;
  const float* x = h + (size_t)row * D_MODEL;
  float4 v = reinterpret_cast<const float4*>(x)[threadIdx.x];
  float s  = v.x + v.y + v.z + v.w;
  float s2 = v.x * v.x + v.y * v.y + v.z * v.z + v.w * v.w;
  for (int m = 1; m < 64; m <<= 1) {
    s  += __shfl_xor(s, m);
    s2 += __shfl_xor(s2, m);
  }
  __shared__ float ls[4], ls2[4];
  int wave = threadIdx.x >> 6;
  if ((threadIdx.x & 63) == 0) { ls[wave] = s; ls2[wave] = s2; }
  __syncthreads();
  s  = ls[0] + ls[1] + ls[2] + ls[3];
  s2 = ls2[0] + ls2[1] + ls2[2] + ls2[3];
  float mu  = s * (1.0f / D_MODEL);
  float var = s2 * (1.0f / D_MODEL) - mu * mu;
  float rs  = rsqrtf(var + LN_EPS);
  int c = threadIdx.x * 4;
  float4 wv = reinterpret_cast<const float4*>(w)[threadIdx.x];
  float4 bv = reinterpret_cast<const float4*>(b)[threadIdx.x];
  ushort4 o;
  o.x = f2bf((v.x - mu) * rs * wv.x + bv.x);
  o.y = f2bf((v.y - mu) * rs * wv.y + bv.y);
  o.z = f2bf((v.z - mu) * rs * wv.z + bv.z);
  o.w = f2bf((v.w - mu) * rs * wv.w + bv.w);
  reinterpret_cast<ushort4*>(hn + (size_t)row * D_MODEL)[threadIdx.x] = o;
}

// ---------------- GEMM: C[M,N] = A[M,K] @ Bt[N,K]^T + bias (+resid) -------
// 64x64 tile, 4 waves of 32x32, mfma_f32_16x16x32_bf16.
// A,Bt bf16 row-major; FINAL: fp32 out with residual; else bf16 out.
template <bool FINAL>
__global__ __launch_bounds__(256) void gemm_bt_kernel(
    const unsigned short* __restrict__ A, const unsigned short* __restrict__ Bt,
    const float* __restrict__ bias, const float* __restrict__ resid,
    unsigned short* __restrict__ Cb, float* __restrict__ Cf,
    int M, int N, int K) {
  __shared__ unsigned short As[64][72];
  __shared__ unsigned short Bs[64][72];

  const int tid  = threadIdx.x;
  const int w    = tid >> 6;
  const int lane = tid & 63;
  const int l15  = lane & 15;
  const int quad = lane >> 4;
  const int wm = (w >> 1) * 32;   // wave M offset in tile
  const int wn = (w & 1) * 32;    // wave N offset in tile

  const int sr = tid >> 2;              // staging row 0..63
  const int sc = (tid & 3) * 16;        // staging col 0..48
  const size_t gra = (size_t)(blockIdx.y * 64 + sr) * K;
  const size_t grb = (size_t)(blockIdx.x * 64 + sr) * K;

  floatx4 acc[2][2];
  for (int i = 0; i < 2; ++i)
    for (int j = 0; j < 2; ++j)
      acc[i][j] = {0.f, 0.f, 0.f, 0.f};

  for (int k0 = 0; k0 < K; k0 += 64) {
    uint4 a0 = *reinterpret_cast<const uint4*>(A + gra + k0 + sc);
    uint4 a1 = *reinterpret_cast<const uint4*>(A + gra + k0 + sc + 8);
    uint4 b0 = *reinterpret_cast<const uint4*>(Bt + grb + k0 + sc);
    uint4 b1 = *reinterpret_cast<const uint4*>(Bt + grb + k0 + sc + 8);
    *reinterpret_cast<uint4*>(&As[sr][sc])     = a0;
    *reinterpret_cast<uint4*>(&As[sr][sc + 8]) = a1;
    *reinterpret_cast<uint4*>(&Bs[sr][sc])     = b0;
    *reinterpret_cast<uint4*>(&Bs[sr][sc + 8]) = b1;
    __syncthreads();

    for (int kb = 0; kb < 2; ++kb) {
      bf16x8 af[2], bf[2];
      for (int mi = 0; mi < 2; ++mi)
        af[mi] = *reinterpret_cast<const bf16x8*>(&As[wm + mi * 16 + l15][kb * 32 + quad * 8]);
      for (int ni = 0; ni < 2; ++ni)
        bf[ni] = *reinterpret_cast<const bf16x8*>(&Bs[wn + ni * 16 + l15][kb * 32 + quad * 8]);
      for (int mi = 0; mi < 2; ++mi)
        for (int ni = 0; ni < 2; ++ni)
          acc[mi][ni] = __builtin_amdgcn_mfma_f32_16x16x32_bf16(af[mi], bf[ni], acc[mi][ni], 0, 0, 0);
    }
    __syncthreads();
  }

  // epilogue: C/D layout col=lane&15, row=quad*4+reg  [m89-verified]
  for (int mi = 0; mi < 2; ++mi) {
    for (int ni = 0; ni < 2; ++ni) {
      int col = blockIdx.x * 64 + wn + ni * 16 + l15;
      float bb = bias[col];
      for (int r = 0; r < 4; ++r) {
        int row = blockIdx.y * 64 + wm + mi * 16 + quad * 4 + r;
        float val = acc[mi][ni][r] + bb;
        if (FINAL) {
          val += resid[(size_t)row * N + col];
          Cf[(size_t)row * N + col] = val;
        } else {
          Cb[(size_t)row * N + col] = f2bf(val);
        }
      }
    }
  }
}

// ---------------- Flash attention: grid (S/64, H, B), 256 thr -------------
// Each wave owns 16 Q rows; K-tiles of 64 keys; online softmax.
__global__ __launch_bounds__(256) void attn_kernel(
    const unsigned short* __restrict__ Q, const unsigned short* __restrict__ Kb,
    const unsigned short* __restrict__ Vb, unsigned short* __restrict__ O) {
  __shared__ unsigned short Ks[64][72];   // [key][dim]
  __shared__ unsigned short Vt[64][72];   // [dim][key] (transposed)
  __shared__ unsigned short Pl[64][72];   // [q-row][key] bf16 P

  const int tid  = threadIdx.x;
  const int w    = tid >> 6;
  const int lane = tid & 63;
  const int l15  = lane & 15;
  const int quad = lane >> 4;

  const int qt = blockIdx.x, hh = blockIdx.y, bz = blockIdx.z;
  const int tq0  = bz * SEQ + qt * 64;
  const int col0 = hh * D_K;

  // Q fragments for this wave's 16 rows (A layout: m=lane&15, k=quad*8+j)
  bf16x8 qf[2];
  for (int kb = 0; kb < 2; ++kb)
    qf[kb] = *reinterpret_cast<const bf16x8*>(
        Q + (size_t)(tq0 + w * 16 + l15) * D_MODEL + col0 + kb * 32 + quad * 8);

  float m_s[4], l_s[4];
  floatx4 oacc[4];
  for (int r = 0; r < 4; ++r) { m_s[r] = -1e30f; l_s[r] = 0.f; }
  for (int d = 0; d < 4; ++d) oacc[d] = {0.f, 0.f, 0.f, 0.f};

  const int sr = tid >> 2;
  const int sc = (tid & 3) * 16;

  for (int kt = 0; kt < SEQ / 64; ++kt) {
    const int tk0 = bz * SEQ + kt * 64;
    // stage K tile [64 keys][64 dims]
    {
      const unsigned short* kp = Kb + (size_t)(tk0 + sr) * D_MODEL + col0 + sc;
      uint4 k0v = *reinterpret_cast<const uint4*>(kp);
      uint4 k1v = *reinterpret_cast<const uint4*>(kp + 8);
      *reinterpret_cast<uint4*>(&Ks[sr][sc])     = k0v;
      *reinterpret_cast<uint4*>(&Ks[sr][sc + 8]) = k1v;
      // stage V transposed: Vt[dim][key]
      const unsigned short* vp = Vb + (size_t)(tk0 + sr) * D_MODEL + col0 + sc;
      union { uint4 u; unsigned short s[8]; } v0, v1;
      v0.u = *reinterpret_cast<const uint4*>(vp);
      v1.u = *reinterpret_cast<const uint4*>(vp + 8);
      for (int j = 0; j < 8; ++j) Vt[sc + j][sr]     = v0.s[j];
      for (int j = 0; j < 8; ++j) Vt[sc + 8 + j][sr] = v1.s[j];
    }
    __syncthreads();

    // scores S[16,64] for this wave: A=Q, B=K-tile rows
    floatx4 sacc[4];
    for (int nb = 0; nb < 4; ++nb) sacc[nb] = {0.f, 0.f, 0.f, 0.f};
    for (int nb = 0; nb < 4; ++nb)
      for (int kb = 0; kb < 2; ++kb) {
        bf16x8 bk = *reinterpret_cast<const bf16x8*>(&Ks[nb * 16 + l15][kb * 32 + quad * 8]);
        sacc[nb] = __builtin_amdgcn_mfma_f32_16x16x32_bf16(qf[kb], bk, sacc[nb], 0, 0, 0);
      }
    for (int nb = 0; nb < 4; ++nb) sacc[nb] *= 0.125f;  // 1/sqrt(64)

    // online softmax update (row r = local row quad*4+r)
    float p[4][4];
    float alpha[4];
    for (int r = 0; r < 4; ++r) {
      float rm = fmaxf(fmaxf(sacc[0][r], sacc[1][r]), fmaxf(sacc[2][r], sacc[3][r]));
      for (int m = 1; m < 16; m <<= 1) rm = fmaxf(rm, __shfl_xor(rm, m));
      float mn = fmaxf(m_s[r], rm);
      alpha[r] = __expf(m_s[r] - mn);
      m_s[r] = mn;
      float rs = 0.f;
      for (int nb = 0; nb < 4; ++nb) {
        p[nb][r] = __expf(sacc[nb][r] - mn);
        rs += p[nb][r];
      }
      for (int m = 1; m < 16; m <<= 1) rs += __shfl_xor(rs, m);
      l_s[r] = l_s[r] * alpha[r] + rs;
    }
    for (int d = 0; d < 4; ++d)
      for (int r = 0; r < 4; ++r) oacc[d][r] *= alpha[r];

    // P: C-layout -> LDS (bf16), rows w*16+quad*4+r, cols nb*16+l15
    for (int nb = 0; nb < 4; ++nb)
      for (int r = 0; r < 4; ++r)
        Pl[w * 16 + quad * 4 + r][nb * 16 + l15] = f2bf(p[nb][r]);
    __syncthreads();

    // PV: A = P (A-layout from LDS), B = Vt rows (d-major)
    for (int kb = 0; kb < 2; ++kb) {
      bf16x8 ap = *reinterpret_cast<const bf16x8*>(&Pl[w * 16 + l15][kb * 32 + quad * 8]);
      for (int d = 0; d < 4; ++d) {
        bf16x8 bv = *reinterpret_cast<const bf16x8*>(&Vt[d * 16 + l15][kb * 32 + quad * 8]);
        oacc[d] = __builtin_amdgcn_mfma_f32_16x16x32_bf16(ap, bv, oacc[d], 0, 0, 0);
      }
    }
    __syncthreads();  // protect Ks/Vt/Pl before next staging
  }

  // finalize: O /= l, write bf16 [token, h*64+d]
  for (int r = 0; r < 4; ++r) {
    float inv = 1.0f / l_s[r];
    int row = tq0 + w * 16 + quad * 4 + r;
    for (int d = 0; d < 4; ++d)
      O[(size_t)row * D_MODEL + col0 + d * 16 + l15] = f2bf(oacc[d][r] * inv);
  }
}

// ---------------- launch ---------------------------------------------------
extern "C" void kernel_launch(void* const* d_in, const int* in_sizes, int n_in,
                              void* d_out, int out_size, void* d_ws, size_t ws_size,
                              hipStream_t stream) {
  const float* h    = (const float*)d_in[0];
  const float* Wq   = (const float*)d_in[1];
  const float* bq   = (const float*)d_in[2];
  const float* Wk   = (const float*)d_in[3];
  const float* bk   = (const float*)d_in[4];
  const float* Wv   = (const float*)d_in[5];
  const float* bv   = (const float*)d_in[6];
  const float* Wo   = (const float*)d_in[7];
  const float* bo   = (const float*)d_in[8];
  const float* ln_w = (const float*)d_in[9];
  const float* ln_b = (const float*)d_in[10];
  float* out = (float*)d_out;

  unsigned short* ws = (unsigned short*)d_ws;
  const size_t WSZ = (size_t)1 << 20;            // 1M elems per weight
  const size_t TSZ = (size_t)TOKENS * D_MODEL;   // 4M elems per activation
  unsigned short* Wqb  = ws;                 // 4 weights, concatenated
  unsigned short* Wkb  = Wqb + WSZ;
  unsigned short* Wvb  = Wkb + WSZ;
  unsigned short* Wob  = Wvb + WSZ;
  unsigned short* hn   = Wob + WSZ;
  unsigned short* Qb   = hn + TSZ;
  unsigned short* Kbuf = Qb + TSZ;
  unsigned short* Vbuf = Kbuf + TSZ;
  unsigned short* Obuf = Vbuf + TSZ;

  convw_kernel<<<4096, 256, 0, stream>>>(Wq, Wk, Wv, Wo, Wqb);
  ln_kernel<<<TOKENS, 256, 0, stream>>>(h, ln_w, ln_b, hn);

  dim3 gg(D_MODEL / 64, TOKENS / 64);  // (16, 64)
  gemm_bt_kernel<false><<<gg, 256, 0, stream>>>(hn, Wqb, bq, nullptr, Qb, nullptr,
                                                TOKENS, D_MODEL, D_MODEL);
  gemm_bt_kernel<false><<<gg, 256, 0, stream>>>(hn, Wkb, bk, nullptr, Kbuf, nullptr,
                                                TOKENS, D_MODEL, D_MODEL);
  gemm_bt_kernel<false><<<gg, 256, 0, stream>>>(hn, Wvb, bv, nullptr, Vbuf, nullptr,
                                                TOKENS, D_MODEL, D_MODEL);

  attn_kernel<<<dim3(SEQ / 64, N_HEADS, BATCH), 256, 0, stream>>>(Qb, Kbuf, Vbuf, Obuf);

  gemm_bt_kernel<true><<<gg, 256, 0, stream>>>(Obuf, Wob, bo, h, nullptr, out,
                                               TOKENS, D_MODEL, D_MODEL);
}